// Round 8
// baseline (336.230 us; speedup 1.0000x reference)
//
#include <hip/hip_runtime.h>
#include <math.h>

#define BB 2
#define SS 512
#define DD 64
#define DDDD 4096   // DD*DD
#define NC 32       // time chunks
#define CL (SS / NC) // 16 chunk length

// -------- Kernel 1: per (b,s) LayerNorm stats + dt + decay; also zeroes k2 flags --------
__global__ __launch_bounds__(256) void k1_stats(
    const float* __restrict__ x, const float* __restrict__ log_A,
    const float* __restrict__ dt_w, const float* __restrict__ dt_b,
    const float* __restrict__ ln_w, const float* __restrict__ ln_b,
    float* __restrict__ a_out, float2* __restrict__ stats,
    unsigned int* __restrict__ flags)
{
    const int bs  = blockIdx.x;       // b*SS + s
    const int tid = threadIdx.x;      // 256 threads x 16 elems

    if (tid < 4) flags[bs * 4 + tid] = 0u;   // 4096 flags total, zeroed pre-k2

    const float4* xp4 = (const float4*)(x + (size_t)bs * DDDD + tid * 16);
    float4 v0 = xp4[0], v1 = xp4[1], v2 = xp4[2], v3 = xp4[3];

    float sum = (v0.x+v0.y+v0.z+v0.w) + (v1.x+v1.y+v1.z+v1.w)
              + (v2.x+v2.y+v2.z+v2.w) + (v3.x+v3.y+v3.z+v3.w);
    float sq  = (v0.x*v0.x+v0.y*v0.y+v0.z*v0.z+v0.w*v0.w)
              + (v1.x*v1.x+v1.y*v1.y+v1.z*v1.z+v1.w*v1.w)
              + (v2.x*v2.x+v2.y*v2.y+v2.z*v2.z+v2.w*v2.w)
              + (v3.x*v3.x+v3.y*v3.y+v3.z*v3.z+v3.w*v3.w);

    #pragma unroll
    for (int off = 32; off > 0; off >>= 1) {
        sum += __shfl_down(sum, off);
        sq  += __shfl_down(sq,  off);
    }
    __shared__ float s_sum[4], s_sq[4];
    const int wv = tid >> 6, ln = tid & 63;
    if (ln == 0) { s_sum[wv] = sum; s_sq[wv] = sq; }
    __syncthreads();
    const float tsum = s_sum[0] + s_sum[1] + s_sum[2] + s_sum[3];
    const float tsq  = s_sq[0]  + s_sq[1]  + s_sq[2]  + s_sq[3];
    const float mu   = tsum * (1.0f / DDDD);
    const float var  = tsq  * (1.0f / DDDD) - mu * mu;
    const float rstd = rsqrtf(var + 1e-5f);

    const float4* lw4 = (const float4*)(ln_w + tid * 16);
    const float4* lb4 = (const float4*)(ln_b + tid * 16);
    const float4* dw4 = (const float4*)(dt_w + (tid & 3) * 16);
    float p = 0.f;
    #define ACC4(vv, ii) { \
        float4 lw = lw4[ii], lb = lb4[ii], dw = dw4[ii];            \
        p = fmaf(fmaf((vv.x - mu) * rstd, lw.x, lb.x), dw.x, p);    \
        p = fmaf(fmaf((vv.y - mu) * rstd, lw.y, lb.y), dw.y, p);    \
        p = fmaf(fmaf((vv.z - mu) * rstd, lw.z, lb.z), dw.z, p);    \
        p = fmaf(fmaf((vv.w - mu) * rstd, lw.w, lb.w), dw.w, p);    \
    }
    ACC4(v0, 0); ACC4(v1, 1); ACC4(v2, 2); ACC4(v3, 3);
    #undef ACC4

    p += __shfl_xor(p, 1);
    p += __shfl_xor(p, 2);

    if ((tid & 3) == 0) {
        const int d = tid >> 2;
        float z = p + dt_b[0];
        float dt = (z > 20.f) ? z : log1pf(expf(z));   // softplus
        float la = dt * (-expf(log_A[d]));             // <= 0 always
        a_out[bs * DD + d] = expf(la);                 // decay in (0,1]
    }
    if (tid == 0) stats[bs] = make_float2(mu, rstd);
}

// -------- Kernel 2: single-pass chunked scan with cross-chunk flag handoff --------
// wave per (b, r, ch); publishes local (F,P), waits for predecessors (all run
// concurrently -> wait is skew, not a chain), combines carry, rescans from regs.
__global__ __launch_bounds__(256) void k2_scan1p(
    const float* __restrict__ x, const float* __restrict__ a_in,
    const float* __restrict__ ln_w, const float* __restrict__ ln_b,
    const float2* __restrict__ stats,
    float* __restrict__ Fbuf, float* __restrict__ Pbuf,
    unsigned int* __restrict__ flags,
    float* __restrict__ out)
{
    const int gw = blockIdx.x * 4 + (threadIdx.x >> 6);   // 0..BB*DD*NC-1
    const int c  = threadIdx.x & 63;
    const int ch = gw & (NC - 1);
    const int br = gw >> 5;                               // log2(NC)=5
    const int b  = br >> 6, r = br & 63;

    const float lnw = ln_w[r * DD + c];
    const float lnb = ln_b[r * DD + c];

    const int t0 = ch * CL;
    const size_t xoff = (((size_t)(b * SS + t0)) * DD + r) * DD + c;
    const float*  xp = x + xoff;
    const float*  ap = a_in + (b * SS + t0) * DD + r;
    const float2* sp = stats + b * SS + t0;

    // ---- Phase 1: local scan; keep xv, xn, a in registers ----
    float xvs[CL], xns[CL], as_[CL];
    float state = 0.f, P = 1.f;
    #pragma unroll
    for (int t = 0; t < CL; t += 8) {
        float xv[8], av[8]; float2 st[8];
        #pragma unroll
        for (int i = 0; i < 8; ++i) {
            xv[i] = xp[(size_t)(t + i) * DDDD];
            av[i] = ap[(t + i) * DD];
            st[i] = sp[t + i];
        }
        #pragma unroll
        for (int i = 0; i < 8; ++i) {
            float xn = fmaf((xv[i] - st[i].x) * st[i].y, lnw, lnb);
            state = fmaf(av[i], state, xn);
            P *= av[i];
            xvs[t + i] = xv[i];
            xns[t + i] = xn;
            as_[t + i] = av[i];
        }
    }

    // ---- Publish local aggregate (F, P) then flag (release) ----
    Fbuf[(size_t)gw * DD + c] = state;
    if (c == 0) Pbuf[gw] = P;
    __threadfence();                     // device-scope: F/P visible before flag
    if (c == 0)
        __hip_atomic_store(&flags[gw], 1u, __ATOMIC_RELAXED, __HIP_MEMORY_SCOPE_AGENT);

    // ---- Wait for all predecessor chunks of this (b,r) ----
    if (c == 0) {
        for (int v = 0; v < ch; ++v) {
            while (__hip_atomic_load(&flags[br * NC + v], __ATOMIC_RELAXED,
                                     __HIP_MEMORY_SCOPE_AGENT) == 0u) {
                __builtin_amdgcn_s_sleep(2);
            }
        }
    }
    __threadfence();                     // acquire: no F/P read hoisted above poll

    // ---- Carry: masked FMA over predecessor aggregates ----
    float carry = 0.f;
    #pragma unroll
    for (int vb = 0; vb < NC; vb += 8) {
        float f[8], p[8];
        #pragma unroll
        for (int i = 0; i < 8; ++i) {
            f[i] = Fbuf[(size_t)(br * NC + vb + i) * DD + c];
            p[i] = Pbuf[br * NC + vb + i];
        }
        #pragma unroll
        for (int i = 0; i < 8; ++i) {
            const int v = vb + i;
            carry = fmaf((v < ch) ? p[i] : 1.f, carry, (v < ch) ? f[i] : 0.f);
        }
    }

    // ---- Phase 2: rescan from registers, write out ----
    float st = carry;
    float* op = out + xoff;
    #pragma unroll
    for (int t = 0; t < CL; ++t) {
        st = fmaf(as_[t], st, xns[t]);
        op[(size_t)t * DDDD] = st + xvs[t];
    }
}

extern "C" void kernel_launch(void* const* d_in, const int* in_sizes, int n_in,
                              void* d_out, int out_size, void* d_ws, size_t ws_size,
                              hipStream_t stream) {
    const float* x     = (const float*)d_in[0];
    const float* log_A = (const float*)d_in[1];
    const float* dt_w  = (const float*)d_in[2];
    const float* dt_b  = (const float*)d_in[3];
    const float* ln_w  = (const float*)d_in[4];
    const float* ln_b  = (const float*)d_in[5];
    float* out = (float*)d_out;

    char* ws = (char*)d_ws;
    float*        a_buf = (float*)ws;                        // 256 KB  [BB*SS][DD]
    float2*       stats = (float2*)(ws + 262144);            //   8 KB  [BB*SS]
    float*        Fbuf  = (float*)(ws + 270336);             //   1 MB  [4096][DD]
    float*        Pbuf  = (float*)(ws + 270336 + 1048576);   //  16 KB  [4096]
    unsigned int* flags = (unsigned int*)(ws + 270336 + 1048576 + 16384); // 16 KB

    k1_stats<<<BB * SS, 256, 0, stream>>>(x, log_A, dt_w, dt_b, ln_w, ln_b,
                                          a_buf, stats, flags);
    k2_scan1p<<<BB * DD * NC / 4, 256, 0, stream>>>(x, a_buf, ln_w, ln_b, stats,
                                                    Fbuf, Pbuf, flags, out);
}

// Round 9
// 96.589 us; speedup vs baseline: 3.4810x; 3.4810x over previous
//
#include <hip/hip_runtime.h>
#include <math.h>

#define BB 2
#define SS 512
#define DD 64
#define DDDD 4096    // DD*DD
#define NC 64        // time chunks
#define CL (SS / NC) // 8 chunk length

// -------- Kernel 1: per (b,s) LayerNorm stats + dt + decay a = exp(dt * -exp(log_A)) --------
__global__ __launch_bounds__(256) void k1_stats(
    const float* __restrict__ x, const float* __restrict__ log_A,
    const float* __restrict__ dt_w, const float* __restrict__ dt_b,
    const float* __restrict__ ln_w, const float* __restrict__ ln_b,
    float* __restrict__ a_out, float2* __restrict__ stats)
{
    const int bs  = blockIdx.x;       // b*SS + s
    const int tid = threadIdx.x;      // 256 threads x 16 elems

    const float4* xp4 = (const float4*)(x + (size_t)bs * DDDD + tid * 16);
    float4 v0 = xp4[0], v1 = xp4[1], v2 = xp4[2], v3 = xp4[3];

    float sum = (v0.x+v0.y+v0.z+v0.w) + (v1.x+v1.y+v1.z+v1.w)
              + (v2.x+v2.y+v2.z+v2.w) + (v3.x+v3.y+v3.z+v3.w);
    float sq  = (v0.x*v0.x+v0.y*v0.y+v0.z*v0.z+v0.w*v0.w)
              + (v1.x*v1.x+v1.y*v1.y+v1.z*v1.z+v1.w*v1.w)
              + (v2.x*v2.x+v2.y*v2.y+v2.z*v2.z+v2.w*v2.w)
              + (v3.x*v3.x+v3.y*v3.y+v3.z*v3.z+v3.w*v3.w);

    #pragma unroll
    for (int off = 32; off > 0; off >>= 1) {
        sum += __shfl_down(sum, off);
        sq  += __shfl_down(sq,  off);
    }
    __shared__ float s_sum[4], s_sq[4];
    const int wv = tid >> 6, ln = tid & 63;
    if (ln == 0) { s_sum[wv] = sum; s_sq[wv] = sq; }
    __syncthreads();
    const float tsum = s_sum[0] + s_sum[1] + s_sum[2] + s_sum[3];
    const float tsq  = s_sq[0]  + s_sq[1]  + s_sq[2]  + s_sq[3];
    const float mu   = tsum * (1.0f / DDDD);
    const float var  = tsq  * (1.0f / DDDD) - mu * mu;
    const float rstd = rsqrtf(var + 1e-5f);

    const float4* lw4 = (const float4*)(ln_w + tid * 16);
    const float4* lb4 = (const float4*)(ln_b + tid * 16);
    const float4* dw4 = (const float4*)(dt_w + (tid & 3) * 16);
    float p = 0.f;
    #define ACC4(vv, ii) { \
        float4 lw = lw4[ii], lb = lb4[ii], dw = dw4[ii];            \
        p = fmaf(fmaf((vv.x - mu) * rstd, lw.x, lb.x), dw.x, p);    \
        p = fmaf(fmaf((vv.y - mu) * rstd, lw.y, lb.y), dw.y, p);    \
        p = fmaf(fmaf((vv.z - mu) * rstd, lw.z, lb.z), dw.z, p);    \
        p = fmaf(fmaf((vv.w - mu) * rstd, lw.w, lb.w), dw.w, p);    \
    }
    ACC4(v0, 0); ACC4(v1, 1); ACC4(v2, 2); ACC4(v3, 3);
    #undef ACC4

    p += __shfl_xor(p, 1);
    p += __shfl_xor(p, 2);

    if ((tid & 3) == 0) {
        const int d = tid >> 2;
        float z = p + dt_b[0];
        float dt = (z > 20.f) ? z : log1pf(expf(z));   // softplus
        float la = dt * (-expf(log_A[d]));             // <= 0 always
        a_out[bs * DD + d] = expf(la);                 // decay in (0,1]
    }
    if (tid == 0) stats[bs] = make_float2(mu, rstd);
}

// Wave layout for the scan kernels: wave per (b, ch, rg).
// lane = sr*16 + cl : covers row r = rg*4+sr, cols c4 = cl*4 .. +3 (float4).
// One wave load per t = 1 KB contiguous (4 rows x 256 B).

// -------- Kernel 2a: per-(b,r,chunk) local scan -> (F float4, P) --------
__global__ __launch_bounds__(256) void k2a_partial(
    const float* __restrict__ x, const float* __restrict__ a_in,
    const float* __restrict__ ln_w, const float* __restrict__ ln_b,
    const float2* __restrict__ stats,
    float* __restrict__ Fbuf, float* __restrict__ Pbuf)
{
    const int gw   = blockIdx.x * 4 + (threadIdx.x >> 6);  // 0..BB*NC*16-1
    const int lane = threadIdx.x & 63;
    const int b  = gw >> 10;                // NC*16 = 1024 per batch
    const int ch = (gw >> 4) & (NC - 1);
    const int rg = gw & 15;
    const int r  = rg * 4 + (lane >> 4);
    const int c4 = (lane & 15) * 4;
    const int t0 = ch * CL;

    const float4 lnw4 = *(const float4*)(ln_w + r * DD + c4);
    const float4 lnb4 = *(const float4*)(ln_b + r * DD + c4);

    const float*  xp = x + (((size_t)(b * SS + t0)) * DD + r) * DD + c4;
    const float*  ap = a_in + (b * SS + t0) * DD + r;
    const float2* sp = stats + b * SS + t0;

    float4 st = make_float4(0.f, 0.f, 0.f, 0.f);
    float  P  = 1.f;
    #pragma unroll
    for (int t = 0; t < CL; ++t) {
        const float4 xv = *(const float4*)(xp + (size_t)t * DDDD);
        const float  av = ap[t * DD];
        const float2 ms = sp[t];
        st.x = fmaf(av, st.x, fmaf((xv.x - ms.x) * ms.y, lnw4.x, lnb4.x));
        st.y = fmaf(av, st.y, fmaf((xv.y - ms.x) * ms.y, lnw4.y, lnb4.y));
        st.z = fmaf(av, st.z, fmaf((xv.z - ms.x) * ms.y, lnw4.z, lnb4.z));
        st.w = fmaf(av, st.w, fmaf((xv.w - ms.x) * ms.y, lnw4.w, lnb4.w));
        P *= av;
    }
    *(float4*)(Fbuf + (((size_t)(b * DD + r)) * NC + ch) * DD + c4) = st;
    if ((lane & 15) == 0) Pbuf[(b * DD + r) * NC + ch] = P;
}

// -------- Kernel 2b: carry over predecessor chunks + rescan + write out --------
__global__ __launch_bounds__(256) void k2b_final(
    const float* __restrict__ x, const float* __restrict__ a_in,
    const float* __restrict__ ln_w, const float* __restrict__ ln_b,
    const float2* __restrict__ stats,
    const float* __restrict__ Fbuf, const float* __restrict__ Pbuf,
    float* __restrict__ out)
{
    const int gw   = blockIdx.x * 4 + (threadIdx.x >> 6);
    const int lane = threadIdx.x & 63;
    const int b  = gw >> 10;
    const int ch = (gw >> 4) & (NC - 1);
    const int rg = gw & 15;
    const int r  = rg * 4 + (lane >> 4);
    const int c4 = (lane & 15) * 4;
    const int t0 = ch * CL;

    // ---- carry: batched loads + predicated FMA chain over NC aggregates ----
    const float* fb = Fbuf + ((size_t)(b * DD + r)) * NC * DD + c4;
    const float* pb = Pbuf + (b * DD + r) * NC;
    float4 carry = make_float4(0.f, 0.f, 0.f, 0.f);
    for (int vb = 0; vb < NC; vb += 8) {
        float4 f[8]; float p[8];
        #pragma unroll
        for (int i = 0; i < 8; ++i) {
            f[i] = *(const float4*)(fb + (size_t)(vb + i) * DD);
            p[i] = pb[vb + i];
        }
        #pragma unroll
        for (int i = 0; i < 8; ++i) {
            const int v = vb + i;
            const bool pre = (v < ch);
            const float pv = pre ? p[i] : 1.f;
            carry.x = fmaf(pv, carry.x, pre ? f[i].x : 0.f);
            carry.y = fmaf(pv, carry.y, pre ? f[i].y : 0.f);
            carry.z = fmaf(pv, carry.z, pre ? f[i].z : 0.f);
            carry.w = fmaf(pv, carry.w, pre ? f[i].w : 0.f);
        }
    }

    const float4 lnw4 = *(const float4*)(ln_w + r * DD + c4);
    const float4 lnb4 = *(const float4*)(ln_b + r * DD + c4);

    const size_t xoff = (((size_t)(b * SS + t0)) * DD + r) * DD + c4;
    const float*  xp = x + xoff;
    const float*  ap = a_in + (b * SS + t0) * DD + r;
    const float2* sp = stats + b * SS + t0;
    float* op = out + xoff;

    float4 st = carry;
    #pragma unroll
    for (int t = 0; t < CL; ++t) {
        const float4 xv = *(const float4*)(xp + (size_t)t * DDDD);
        const float  av = ap[t * DD];
        const float2 ms = sp[t];
        st.x = fmaf(av, st.x, fmaf((xv.x - ms.x) * ms.y, lnw4.x, lnb4.x));
        st.y = fmaf(av, st.y, fmaf((xv.y - ms.x) * ms.y, lnw4.y, lnb4.y));
        st.z = fmaf(av, st.z, fmaf((xv.z - ms.x) * ms.y, lnw4.z, lnb4.z));
        st.w = fmaf(av, st.w, fmaf((xv.w - ms.x) * ms.y, lnw4.w, lnb4.w));
        float4 o;
        o.x = st.x + xv.x; o.y = st.y + xv.y;
        o.z = st.z + xv.z; o.w = st.w + xv.w;
        *(float4*)(op + (size_t)t * DDDD) = o;
    }
}

extern "C" void kernel_launch(void* const* d_in, const int* in_sizes, int n_in,
                              void* d_out, int out_size, void* d_ws, size_t ws_size,
                              hipStream_t stream) {
    const float* x     = (const float*)d_in[0];
    const float* log_A = (const float*)d_in[1];
    const float* dt_w  = (const float*)d_in[2];
    const float* dt_b  = (const float*)d_in[3];
    const float* ln_w  = (const float*)d_in[4];
    const float* ln_b  = (const float*)d_in[5];
    float* out = (float*)d_out;

    char* ws = (char*)d_ws;
    float*  a_buf = (float*)ws;                              // 256 KB [BB*SS][DD]
    float2* stats = (float2*)(ws + (256 << 10));             //   8 KB [BB*SS]
    float*  Fbuf  = (float*)(ws + (264 << 10));              //   2 MB [BB*DD][NC][DD]
    float*  Pbuf  = (float*)(ws + (264 << 10) + (2 << 20));  //  32 KB [BB*DD][NC]

    k1_stats<<<BB * SS, 256, 0, stream>>>(x, log_A, dt_w, dt_b, ln_w, ln_b, a_buf, stats);
    k2a_partial<<<BB * NC * 16 / 4, 256, 0, stream>>>(x, a_buf, ln_w, ln_b, stats, Fbuf, Pbuf);
    k2b_final<<<BB * NC * 16 / 4, 256, 0, stream>>>(x, a_buf, ln_w, ln_b, stats, Fbuf, Pbuf, out);
}